// Round 1
// 92.713 us; speedup vs baseline: 1.0887x; 1.0887x over previous
//
#include <hip/hip_runtime.h>

#define H_IMG 384
#define W_IMG 640
#define NPAIR 4
#define NBATCH 8
#define NBOX 100
#define DHID 256
#define ROWTILE 8
#define NTILES (H_IMG / ROWTILE)   // 48

// ---------------------------------------------------------------------------
// Kernel A: one block per (pair, row-tile): 4*48 = 192 blocks x 256 threads.
//  Step 1: for the tile's 8 rows (2 per wave): diff = |sum_c img[2p+1] - sum_c img[2p]|,
//          fp32 inclusive row scan. The 5 float2-chunks are scanned INDEPENDENTLY
//          (6 rounds of 5 pipelined shuffles) and combined with chunk-total
//          prefixes -- no serial carry chain between chunks.
//  Step 2: column scan over the 8 LDS rows, write tile-local SAT to global
//          + per-column tile totals (transposed layout [p][c][tile]).
// ---------------------------------------------------------------------------
__global__ __launch_bounds__(256) void k_sat_tile(const float* __restrict__ images,
                                                  float* __restrict__ sat,
                                                  float* __restrict__ totals_t) {
    __shared__ float buf[ROWTILE][W_IMG];   // 20 KB

    const int p    = blockIdx.x / NTILES;    // pair
    const int tile = blockIdx.x % NTILES;    // row tile
    const int lane = threadIdx.x & 63;
    const int wv   = threadIdx.x >> 6;       // wave 0..3
    const int r_lo = tile * ROWTILE;

    const size_t chw  = (size_t)H_IMG * W_IMG;
    const size_t chw2 = chw / 2;

    // ---- Step 1: diff + row scan, 2 rows per wave ----
    for (int rr = wv; rr < ROWTILE; rr += 4) {
        const int h = r_lo + rr;
        const float2* i0 = (const float2*)(images + ((size_t)(2 * p)     * 3 * H_IMG + h) * W_IMG);
        const float2* i1 = (const float2*)(images + ((size_t)(2 * p + 1) * 3 * H_IMG + h) * W_IMG);

        float dxv[5], dyv[5], s[5];
        #pragma unroll
        for (int k = 0; k < 5; ++k) {
            const int e = k * 64 + lane;     // float2 index within row (coalesced)
            float2 a0 = i0[e], b0 = i0[e + chw2], c0 = i0[e + 2 * chw2];
            float2 a1 = i1[e], b1 = i1[e + chw2], c1 = i1[e + 2 * chw2];
            dxv[k] = fabsf(((a1.x + b1.x) + c1.x) - ((a0.x + b0.x) + c0.x));
            dyv[k] = fabsf(((a1.y + b1.y) + c1.y) - ((a0.y + b0.y) + c0.y));
            s[k]   = dxv[k] + dyv[k];
        }

        // 5 independent inclusive wave scans, pipelined per round
        #pragma unroll
        for (int off = 1; off < 64; off <<= 1) {
            float u0 = __shfl_up(s[0], off, 64);
            float u1 = __shfl_up(s[1], off, 64);
            float u2 = __shfl_up(s[2], off, 64);
            float u3 = __shfl_up(s[3], off, 64);
            float u4 = __shfl_up(s[4], off, 64);
            if (lane >= off) {
                s[0] += u0; s[1] += u1; s[2] += u2; s[3] += u3; s[4] += u4;
            }
        }

        // chunk totals -> chunk base offsets (4 serial adds, cheap)
        const float t0 = __shfl(s[0], 63, 64);
        const float t1 = __shfl(s[1], 63, 64);
        const float t2 = __shfl(s[2], 63, 64);
        const float t3 = __shfl(s[3], 63, 64);
        float base[5];
        base[0] = 0.0f;
        base[1] = t0;
        base[2] = t0 + t1;
        base[3] = base[2] + t2;
        base[4] = base[3] + t3;

        float2* brow = (float2*)buf[rr];
        #pragma unroll
        for (int k = 0; k < 5; ++k) {
            const int e = k * 64 + lane;
            const float excl = base[k] + s[k] - (dxv[k] + dyv[k]);
            brow[e] = make_float2(excl + dxv[k], excl + dxv[k] + dyv[k]);
        }
    }
    __syncthreads();

    // ---- Step 2: column scan within tile ----
    const int t = threadIdx.x;
    #pragma unroll
    for (int sub = 0; sub < 3; ++sub) {
        const int c = sub * 256 + t;
        if (c < W_IMG) {
            float run = 0.0f;
            float* gcol = sat + ((size_t)p * H_IMG + r_lo) * W_IMG + c;
            #pragma unroll
            for (int i = 0; i < ROWTILE; ++i) {
                run += buf[i][c];
                gcol[(size_t)i * W_IMG] = run;
            }
            totals_t[((size_t)p * W_IMG + c) * NTILES + tile] = run;
        }
    }
}

// ---------------------------------------------------------------------------
// Kernel B: one block per batch (8 blocks x 256).
//  Phase A: per-column exclusive scan of 48 contiguous tile totals -> LDS.
//  Phase B: box scores via SAT(r,c) = local[r][c] + s_off[r/8][c] (O(1)).
//  Phase C: wave-parallel top-2 (tie-break matches jax.lax.top_k: lower idx).
//  Phase D: gather hidden states + fused Linear + interleaved output.
// ---------------------------------------------------------------------------
__global__ __launch_bounds__(256) void k_score_topk_fc(
        const float* __restrict__ sat,
        const float* __restrict__ totals_t,
        const float* __restrict__ pred_boxes,
        const float* __restrict__ lhs,
        const float* __restrict__ fc_w,
        const float* __restrict__ fc_b,
        float* __restrict__ out) {
    const int b = blockIdx.x;
    const int t = threadIdx.x;
    const int p = b >> 1;

    __shared__ float s_off[NTILES][W_IMG];   // 120 KB
    __shared__ float s_score[NBOX];
    __shared__ int   s_idx[2];
    __shared__ float s_h[2][DHID];

    // Phase A: contiguous 48-float read per column, exclusive scan in regs
    for (int c = t; c < W_IMG; c += 256) {
        const float4* tp = (const float4*)(totals_t + ((size_t)p * W_IMG + c) * NTILES);
        float run = 0.0f;
        #pragma unroll
        for (int q = 0; q < NTILES / 4; ++q) {
            const float4 v = tp[q];
            s_off[q * 4 + 0][c] = run; run += v.x;
            s_off[q * 4 + 1][c] = run; run += v.y;
            s_off[q * 4 + 2][c] = run; run += v.z;
            s_off[q * 4 + 3][c] = run; run += v.w;
        }
    }
    __syncthreads();

    const float* S = sat + (size_t)p * H_IMG * W_IMG;

    // Phase B: scores
    if (t < NBOX) {
        const float* pb = pred_boxes + ((size_t)b * NBOX + t) * 4;
        const float cx = pb[0], cy = pb[1], bw = pb[2], bh = pb[3];
        const int bb0 = (int)((cx - 0.5f * bw) * 640.0f);   // vs row index
        const int bb1 = (int)((cy - 0.5f * bh) * 384.0f);   // vs col index
        const int bb2 = (int)((cx + 0.5f * bw) * 640.0f);
        const int bb3 = (int)((cy + 0.5f * bh) * 384.0f);
        const int r0 = bb0 > 0 ? bb0 : 0;
        const int r2 = bb2 < H_IMG - 1 ? bb2 : H_IMG - 1;
        const int c0 = bb1 > 0 ? bb1 : 0;
        const int c2 = bb3 < W_IMG - 1 ? bb3 : W_IMG - 1;
        float sc = 0.0f;
        if (r0 <= r2 && c0 <= c2) {
            float sum = S[(size_t)r2 * W_IMG + c2] + s_off[r2 >> 3][c2];
            if (r0 > 0) sum -= S[(size_t)(r0 - 1) * W_IMG + c2] + s_off[(r0 - 1) >> 3][c2];
            if (c0 > 0) sum -= S[(size_t)r2 * W_IMG + (c0 - 1)] + s_off[r2 >> 3][c0 - 1];
            if (r0 > 0 && c0 > 0)
                sum += S[(size_t)(r0 - 1) * W_IMG + (c0 - 1)] + s_off[(r0 - 1) >> 3][c0 - 1];
            sc = sum / (float)(H_IMG * W_IMG);
        }
        s_score[t] = sc;
    }
    __syncthreads();

    // Phase C: wave-parallel top-2. Order: (score desc, index asc) == jax top_k.
    if (t < 64) {
        float b0 = s_score[t];
        int   i0 = t;
        float b1 = -1e30f;
        int   i1 = 0x7fffffff;
        if (t + 64 < NBOX) {
            const float s1 = s_score[t + 64];
            if (s1 > b0) { b1 = b0; i1 = i0; b0 = s1; i0 = t + 64; }
            else         { b1 = s1; i1 = t + 64; }
        }
        #pragma unroll
        for (int off = 32; off > 0; off >>= 1) {
            const float o0 = __shfl_xor(b0, off, 64);
            const float o1 = __shfl_xor(b1, off, 64);
            const int   j0 = __shfl_xor(i0, off, 64);
            const int   j1 = __shfl_xor(i1, off, 64);
            const bool other_first = (o0 > b0) || (o0 == b0 && j0 < i0);
            if (other_first) {
                // new first = (o0,j0); second = better of (b0,i0) vs (o1,j1)
                const bool mine2 = (b0 > o1) || (b0 == o1 && i0 < j1);
                const float n1 = mine2 ? b0 : o1;
                const int  nj1 = mine2 ? i0 : j1;
                b0 = o0; i0 = j0; b1 = n1; i1 = nj1;
            } else {
                const bool oth2 = (o0 > b1) || (o0 == b1 && j0 < i1);
                if (oth2) { b1 = o0; i1 = j0; }
            }
        }
        if (t == 0) { s_idx[0] = i0; s_idx[1] = i1; }
    }
    __syncthreads();

    // Phase D: gather + Linear
    s_h[0][t] = lhs[((size_t)b * NBOX + s_idx[0]) * DHID + t];
    s_h[1][t] = lhs[((size_t)b * NBOX + s_idx[1]) * DHID + t];
    __syncthreads();

    const float4* wrow4 = (const float4*)(fc_w + (size_t)t * DHID);
    float acc0 = fc_b[t];
    float acc1 = acc0;
    #pragma unroll 8
    for (int d4 = 0; d4 < DHID / 4; ++d4) {
        const float4 wv = wrow4[d4];
        const int d = d4 * 4;
        acc0 = fmaf(s_h[0][d + 0], wv.x, acc0);
        acc0 = fmaf(s_h[0][d + 1], wv.y, acc0);
        acc0 = fmaf(s_h[0][d + 2], wv.z, acc0);
        acc0 = fmaf(s_h[0][d + 3], wv.w, acc0);
        acc1 = fmaf(s_h[1][d + 0], wv.x, acc1);
        acc1 = fmaf(s_h[1][d + 1], wv.y, acc1);
        acc1 = fmaf(s_h[1][d + 2], wv.z, acc1);
        acc1 = fmaf(s_h[1][d + 3], wv.w, acc1);
    }

    const size_t base = (size_t)(b & 1) * (NPAIR * 2 * DHID) + (size_t)(b >> 1) * (2 * DHID);
    out[base + t]        = acc0;
    out[base + DHID + t] = acc1;
}

extern "C" void kernel_launch(void* const* d_in, const int* in_sizes, int n_in,
                              void* d_out, int out_size, void* d_ws, size_t ws_size,
                              hipStream_t stream) {
    const float* images     = (const float*)d_in[0];
    const float* pred_boxes = (const float*)d_in[2];
    const float* lhs        = (const float*)d_in[3];
    const float* fc_w       = (const float*)d_in[4];
    const float* fc_b       = (const float*)d_in[5];
    float* out              = (float*)d_out;

    float* sat      = (float*)d_ws;                              // 3.93 MB
    float* totals_t = sat + (size_t)NPAIR * H_IMG * W_IMG;       // 480 KB, 64B-aligned

    hipLaunchKernelGGL(k_sat_tile, dim3(NPAIR * NTILES), dim3(256), 0, stream,
                       images, sat, totals_t);
    hipLaunchKernelGGL(k_score_topk_fc, dim3(NBATCH), dim3(256), 0, stream,
                       sat, totals_t, pred_boxes, lhs, fc_w, fc_b, out);
}

// Round 2
// 88.595 us; speedup vs baseline: 1.1393x; 1.0465x over previous
//
#include <hip/hip_runtime.h>

#define H_IMG 384
#define W_IMG 640
#define NPAIR 4
#define NBATCH 8
#define NBOX 100
#define DHID 256
#define ROWTILE 6
#define NTILES (H_IMG / ROWTILE)   // 64

// ---------------------------------------------------------------------------
// Kernel A: one block per (pair, row-tile): 4*64 = 256 blocks x 384 threads
//  (exactly 1 block per CU; 6 waves, one image row each).
//  Step 1: diff = |sum_c img[2p+1] - sum_c img[2p]| for the wave's row,
//          fp32 inclusive row scan (5 independent float2-chunk scans,
//          combined with chunk-total prefixes; no serial carry chain).
//  Step 2: in-place column scan over the 6 LDS rows -> tile-local 2D SAT.
//  Step 3: each of the pair's 200 boxes (2 batches x 100) evaluates its
//          rectangle-sum restricted to this tile in O(1) LDS reads and
//          writes partial[b][n][tile] (tile-contiguous for kernel B).
//  No global SAT is materialized: 23.6 MB in, 205 KB out.
// ---------------------------------------------------------------------------
__global__ __launch_bounds__(384) void k_tile_partial(const float* __restrict__ images,
                                                      const float* __restrict__ pred_boxes,
                                                      float* __restrict__ partial) {
    __shared__ float buf[ROWTILE][W_IMG];   // 15.4 KB

    const int p    = blockIdx.x >> 6;        // pair
    const int tile = blockIdx.x & 63;        // row tile
    const int t    = threadIdx.x;
    const int lane = t & 63;
    const int wv   = t >> 6;                 // wave 0..5
    const int r_lo = tile * ROWTILE;

    const size_t chw2 = (size_t)H_IMG * W_IMG / 2;   // float2 per channel

    // ---- Step 1: diff + row scan, 1 row per wave ----
    {
        const int h = r_lo + wv;
        const float2* i0 = (const float2*)(images + ((size_t)(2 * p)     * 3 * H_IMG + h) * W_IMG);
        const float2* i1 = (const float2*)(images + ((size_t)(2 * p + 1) * 3 * H_IMG + h) * W_IMG);

        float dxv[5], dyv[5], s[5];
        #pragma unroll
        for (int k = 0; k < 5; ++k) {
            const int e = k * 64 + lane;     // float2 index within row (coalesced)
            float2 a0 = i0[e], b0 = i0[e + chw2], c0 = i0[e + 2 * chw2];
            float2 a1 = i1[e], b1 = i1[e + chw2], c1 = i1[e + 2 * chw2];
            dxv[k] = fabsf(((a1.x + b1.x) + c1.x) - ((a0.x + b0.x) + c0.x));
            dyv[k] = fabsf(((a1.y + b1.y) + c1.y) - ((a0.y + b0.y) + c0.y));
            s[k]   = dxv[k] + dyv[k];
        }

        // 5 independent inclusive wave scans, pipelined per round
        #pragma unroll
        for (int off = 1; off < 64; off <<= 1) {
            float u0 = __shfl_up(s[0], off, 64);
            float u1 = __shfl_up(s[1], off, 64);
            float u2 = __shfl_up(s[2], off, 64);
            float u3 = __shfl_up(s[3], off, 64);
            float u4 = __shfl_up(s[4], off, 64);
            if (lane >= off) {
                s[0] += u0; s[1] += u1; s[2] += u2; s[3] += u3; s[4] += u4;
            }
        }

        const float t0 = __shfl(s[0], 63, 64);
        const float t1 = __shfl(s[1], 63, 64);
        const float t2 = __shfl(s[2], 63, 64);
        const float t3 = __shfl(s[3], 63, 64);
        float base[5];
        base[0] = 0.0f;
        base[1] = t0;
        base[2] = t0 + t1;
        base[3] = base[2] + t2;
        base[4] = base[3] + t3;

        float2* brow = (float2*)buf[wv];
        #pragma unroll
        for (int k = 0; k < 5; ++k) {
            const int e = k * 64 + lane;
            const float excl = base[k] + s[k] - (dxv[k] + dyv[k]);
            brow[e] = make_float2(excl + dxv[k], excl + dxv[k] + dyv[k]);
        }
    }
    __syncthreads();

    // ---- Step 2: in-place column scan -> full tile-local SAT ----
    for (int c = t; c < W_IMG; c += 384) {
        float run = 0.0f;
        #pragma unroll
        for (int i = 0; i < ROWTILE; ++i) { run += buf[i][c]; buf[i][c] = run; }
    }
    __syncthreads();

    // ---- Step 3: per-box tile-partial rectangle sums ----
    if (t < 2 * NBOX) {
        const int bb = t / NBOX;             // which batch of the pair
        const int n  = t - bb * NBOX;
        const int b  = 2 * p + bb;
        const float* pb = pred_boxes + ((size_t)b * NBOX + n) * 4;
        const float cx = pb[0], cy = pb[1], bw = pb[2], bh = pb[3];
        const int bb0 = (int)((cx - 0.5f * bw) * 640.0f);   // vs row index
        const int bb1 = (int)((cy - 0.5f * bh) * 384.0f);   // vs col index
        const int bb2 = (int)((cx + 0.5f * bw) * 640.0f);
        const int bb3 = (int)((cy + 0.5f * bh) * 384.0f);
        const int r0 = bb0 > 0 ? bb0 : 0;
        const int r2 = bb2 < H_IMG - 1 ? bb2 : H_IMG - 1;
        const int c0 = bb1 > 0 ? bb1 : 0;
        const int c2 = bb3 < W_IMG - 1 ? bb3 : W_IMG - 1;

        const int a  = r0 > r_lo ? r0 : r_lo;                        // clip to tile
        const int e  = r2 < r_lo + ROWTILE - 1 ? r2 : r_lo + ROWTILE - 1;

        float sc = 0.0f;
        if (a <= e && c0 <= c2) {
            const int ie = e - r_lo;
            const int ia = a - r_lo - 1;      // -1 .. ROWTILE-2
            float sum = buf[ie][c2];
            if (ia >= 0) sum -= buf[ia][c2];
            if (c0 > 0) {
                sum -= buf[ie][c0 - 1];
                if (ia >= 0) sum += buf[ia][c0 - 1];
            }
            sc = sum;
        }
        partial[((size_t)b * NBOX + n) * NTILES + tile] = sc;
    }
}

// ---------------------------------------------------------------------------
// Kernel B: one block per batch (8 blocks x 256).
//  Phase A: score[n] = sum of 64 contiguous tile partials (16 float4 loads,
//           deterministic order). Normalization constant dropped: scores are
//           only used for ranking.
//  Phase B: wave-parallel top-2 (tie-break matches jax.lax.top_k: lower idx).
//  Phase C: gather hidden states + fused Linear + interleaved output.
// ---------------------------------------------------------------------------
__global__ __launch_bounds__(256) void k_topk_fc(
        const float* __restrict__ partial,
        const float* __restrict__ lhs,
        const float* __restrict__ fc_w,
        const float* __restrict__ fc_b,
        float* __restrict__ out) {
    const int b = blockIdx.x;
    const int t = threadIdx.x;

    __shared__ float s_score[NBOX];
    __shared__ int   s_idx[2];
    __shared__ float s_h[2][DHID];

    // Phase A: per-box reduction of tile partials
    if (t < NBOX) {
        const float4* pp = (const float4*)(partial + ((size_t)b * NBOX + t) * NTILES);
        float a0 = 0.0f, a1 = 0.0f, a2 = 0.0f, a3 = 0.0f;
        #pragma unroll
        for (int q = 0; q < NTILES / 4; ++q) {
            const float4 v = pp[q];
            a0 += v.x; a1 += v.y; a2 += v.z; a3 += v.w;
        }
        s_score[t] = (a0 + a1) + (a2 + a3);
    }
    __syncthreads();

    // Phase B: wave-parallel top-2. Order: (score desc, index asc) == jax top_k.
    if (t < 64) {
        float b0 = s_score[t];
        int   i0 = t;
        float b1 = -1e30f;
        int   i1 = 0x7fffffff;
        if (t + 64 < NBOX) {
            const float s1 = s_score[t + 64];
            if (s1 > b0) { b1 = b0; i1 = i0; b0 = s1; i0 = t + 64; }
            else         { b1 = s1; i1 = t + 64; }
        }
        #pragma unroll
        for (int off = 32; off > 0; off >>= 1) {
            const float o0 = __shfl_xor(b0, off, 64);
            const float o1 = __shfl_xor(b1, off, 64);
            const int   j0 = __shfl_xor(i0, off, 64);
            const int   j1 = __shfl_xor(i1, off, 64);
            const bool other_first = (o0 > b0) || (o0 == b0 && j0 < i0);
            if (other_first) {
                const bool mine2 = (b0 > o1) || (b0 == o1 && i0 < j1);
                const float n1 = mine2 ? b0 : o1;
                const int  nj1 = mine2 ? i0 : j1;
                b0 = o0; i0 = j0; b1 = n1; i1 = nj1;
            } else {
                const bool oth2 = (o0 > b1) || (o0 == b1 && j0 < i1);
                if (oth2) { b1 = o0; i1 = j0; }
            }
        }
        if (t == 0) { s_idx[0] = i0; s_idx[1] = i1; }
    }
    __syncthreads();

    // Phase C: gather + Linear
    s_h[0][t] = lhs[((size_t)b * NBOX + s_idx[0]) * DHID + t];
    s_h[1][t] = lhs[((size_t)b * NBOX + s_idx[1]) * DHID + t];
    __syncthreads();

    const float4* wrow4 = (const float4*)(fc_w + (size_t)t * DHID);
    float acc0 = fc_b[t];
    float acc1 = acc0;
    #pragma unroll 8
    for (int d4 = 0; d4 < DHID / 4; ++d4) {
        const float4 wv = wrow4[d4];
        const int d = d4 * 4;
        acc0 = fmaf(s_h[0][d + 0], wv.x, acc0);
        acc0 = fmaf(s_h[0][d + 1], wv.y, acc0);
        acc0 = fmaf(s_h[0][d + 2], wv.z, acc0);
        acc0 = fmaf(s_h[0][d + 3], wv.w, acc0);
        acc1 = fmaf(s_h[1][d + 0], wv.x, acc1);
        acc1 = fmaf(s_h[1][d + 1], wv.y, acc1);
        acc1 = fmaf(s_h[1][d + 2], wv.z, acc1);
        acc1 = fmaf(s_h[1][d + 3], wv.w, acc1);
    }

    const size_t base = (size_t)(b & 1) * (NPAIR * 2 * DHID) + (size_t)(b >> 1) * (2 * DHID);
    out[base + t]        = acc0;
    out[base + DHID + t] = acc1;
}

extern "C" void kernel_launch(void* const* d_in, const int* in_sizes, int n_in,
                              void* d_out, int out_size, void* d_ws, size_t ws_size,
                              hipStream_t stream) {
    const float* images     = (const float*)d_in[0];
    const float* pred_boxes = (const float*)d_in[2];
    const float* lhs        = (const float*)d_in[3];
    const float* fc_w       = (const float*)d_in[4];
    const float* fc_b       = (const float*)d_in[5];
    float* out              = (float*)d_out;

    float* partial = (float*)d_ws;   // 8 * 100 * 64 * 4 B = 204.8 KB

    hipLaunchKernelGGL(k_tile_partial, dim3(NPAIR * NTILES), dim3(384), 0, stream,
                       images, pred_boxes, partial);
    hipLaunchKernelGGL(k_topk_fc, dim3(NBATCH), dim3(256), 0, stream,
                       partial, lhs, fc_w, fc_b, out);
}